// Round 8
// baseline (503.589 us; speedup 1.0000x reference)
//
#include <hip/hip_runtime.h>
#include <hip/hip_fp16.h>

static inline int cdiv(long long a, long long b) { return (int)((a + b - 1) / b); }

typedef _Float16 half8 __attribute__((ext_vector_type(8)));
typedef float f32x4 __attribute__((ext_vector_type(4)));

#define NBSH 8          // 256 dsts per bucket
#define BPAD 16         // bucket cursor padding (ints) = 64B -> one L2 line per cursor

// ---------------- CSR build ----------------
__global__ void k_zero_i(int* p, int n) {
    int t = blockIdx.x * blockDim.x + threadIdx.x;
    if (t < n) p[t] = 0;
}

__global__ void k_count(const int* __restrict__ dst, int* __restrict__ deg, int E) {
    int t = blockIdx.x * blockDim.x + threadIdx.x;
    if (t < E) atomicAdd(&deg[dst[t]], 1);
}

__global__ __launch_bounds__(1024) void k_scan1(const int* __restrict__ deg,
                                                int* __restrict__ tmp,
                                                int* __restrict__ bsum, int n) {
    __shared__ int s[1024];
    const int t = threadIdx.x;
    const int i = blockIdx.x * 1024 + t;
    int v = (i < n) ? deg[i] : 0;
    s[t] = v;
    __syncthreads();
    for (int off = 1; off < 1024; off <<= 1) {
        int u = (t >= off) ? s[t - off] : 0;
        __syncthreads();
        s[t] += u;
        __syncthreads();
    }
    if (i < n) tmp[i] = s[t];
    if (t == 1023) bsum[blockIdx.x] = s[1023];
}

__global__ __launch_bounds__(1024) void k_scan2(int* __restrict__ bsum, int nb) {
    __shared__ int s[1024];
    const int t = threadIdx.x;
    s[t] = (t < nb) ? bsum[t] : 0;
    __syncthreads();
    for (int off = 1; off < 1024; off <<= 1) {
        int u = (t >= off) ? s[t - off] : 0;
        __syncthreads();
        s[t] += u;
        __syncthreads();
    }
    if (t < nb) bsum[t] = s[t];
}

// phase 3 (fused): row_ptr, dis = rsqrt(deg+1), bucket cursors, optional per-dst cursors
__global__ __launch_bounds__(1024) void k_scan3(const int* __restrict__ deg,
                                                const int* __restrict__ tmp,
                                                const int* __restrict__ bsum,
                                                int* __restrict__ row_ptr,
                                                float* __restrict__ dis,
                                                int* __restrict__ bcur,
                                                int* __restrict__ cur,  // may be null
                                                int n, int nb) {
    const int i = blockIdx.x * 1024 + threadIdx.x;
    if (i < n) {
        int off = (blockIdx.x == 0) ? 0 : bsum[blockIdx.x - 1];
        int dgi = deg[i];
        int r = tmp[i] - dgi + off;
        row_ptr[i] = r;
        dis[i] = rsqrtf((float)(dgi + 1));  // +1 self-loop
        if ((i & ((1 << NBSH) - 1)) == 0) bcur[(i >> NBSH) * BPAD] = r;
        if (cur) cur[i] = r;
    } else if (i == n) {
        row_ptr[n] = bsum[nb - 1];
    }
}

// pass A: scatter {src,dst} into bucket-contiguous regions (sequential-per-bucket writes)
__global__ void k_passA(const int* __restrict__ ei, int* __restrict__ bcur,
                        int2* __restrict__ ebuf, int E) {
    int e = blockIdx.x * blockDim.x + threadIdx.x;
    if (e >= E) return;
    int s = ei[e];
    int d = ei[e + E];
    int pos = atomicAdd(&bcur[(d >> NBSH) * BPAD], 1);
    ebuf[pos] = make_int2(s, d);
}

// pass B: one block per bucket; per-dst cursors in LDS; writes csr {src,w} into a
// small contiguous window (L2-resident) -> no write amplification.
__global__ __launch_bounds__(256) void k_passB(const int* __restrict__ row_ptr,
                                               const float* __restrict__ dis,
                                               const int2* __restrict__ ebuf,
                                               int2* __restrict__ csr, int N) {
    __shared__ int lcur[1 << NBSH];
    const int d0 = blockIdx.x << NBSH;
    const int dn = min(1 << NBSH, N - d0);
    for (int i = threadIdx.x; i < dn; i += 256) lcur[i] = row_ptr[d0 + i];
    __syncthreads();
    const int lo = row_ptr[d0];
    const int dend = d0 + dn;
    const int hi = row_ptr[dend];
    for (int e = lo + threadIdx.x; e < hi; e += 256) {
        int2 sd = ebuf[e];
        float w = dis[sd.x] * dis[sd.y];
        int pos = atomicAdd(&lcur[sd.y - d0], 1);
        csr[pos] = make_int2(sd.x, __float_as_int(w));
    }
}

// fallback direct scatter (if ws too small for ebuf)
__global__ void k_scatter(const int* __restrict__ ei, const float* __restrict__ dis,
                          int* __restrict__ cur, int2* __restrict__ csr, int E) {
    int e = blockIdx.x * blockDim.x + threadIdx.x;
    if (e >= E) return;
    int s = ei[e];
    int d = ei[e + E];
    float w = dis[s] * dis[d];
    int pos = atomicAdd(&cur[d], 1);
    csr[pos] = make_int2(s, __float_as_int(w));
}

// ---------------- fp32 -> fp16 convert ----------------
__global__ __launch_bounds__(256) void k_cvt_h(const float* __restrict__ in,
                                               __half* __restrict__ out, long long n4) {
    long long t = (long long)blockIdx.x * blockDim.x + threadIdx.x;
    if (t >= n4) return;
    float4 v = *(const float4*)(in + t * 4);
    union { float2 f; __half2 h[2]; } u;
    u.h[0] = __floats2half2_rn(v.x, v.y);
    u.h[1] = __floats2half2_rn(v.z, v.w);
    *(float2*)(out + t * 4) = u.f;
}

// ---------------- weight prep: W fp32 [K][CN] -> swizzled fp16 W^T [CN][K] ----------------
template <int K, int CN>
__global__ void k_prep_wt(const float* __restrict__ W, char* __restrict__ wt) {
    constexpr int CH = K / 8;
    int id = blockIdx.x * blockDim.x + threadIdx.x;
    if (id >= CN * CH) return;
    int n = id / CH, c = id % CH;
    half8 h;
#pragma unroll
    for (int j = 0; j < 8; ++j) h[j] = (_Float16)W[(size_t)(c * 8 + j) * CN + n];
    *(half8*)(wt + (size_t)n * (2 * K) + ((c * 16) ^ ((n & 7) << 4))) = h;
}

// ---------------- fused aggregation: one wave per output row ----------------
template <int C, bool BIAS, bool RELU, bool HIN, bool HOUT>
__global__ __launch_bounds__(256) void k_agg_csr(const int* __restrict__ row_ptr,
                                                 const int2* __restrict__ csr,
                                                 const float* __restrict__ dis,
                                                 const void* __restrict__ in_, int ins,
                                                 void* __restrict__ out_, int outs,
                                                 const float* __restrict__ bias, int N) {
    constexpr int VL = C / 64;
    const int wave = (int)(((long long)blockIdx.x * blockDim.x + threadIdx.x) >> 6);
    const int lane = threadIdx.x & 63;
    if (wave >= N) return;
    const int d = wave;
    const int c = lane * VL;
    const float dd = dis[d];
    const float wself = dd * dd;

    auto ld2 = [&](int row) -> float2 {
        if constexpr (HIN) {
            __half2 h = *(const __half2*)((const __half*)in_ + (size_t)row * ins + c);
            return __half22float2(h);
        } else {
            return *(const float2*)((const float*)in_ + (size_t)row * ins + c);
        }
    };
    auto ld1 = [&](int row) -> float {
        if constexpr (HIN) {
            return __half2float(((const __half*)in_)[(size_t)row * ins + c]);
        } else {
            return ((const float*)in_)[(size_t)row * ins + c];
        }
    };

    float acc[VL];
    if (VL == 2) {
        float2 v = ld2(d);
        acc[0] = wself * v.x;
        acc[1] = wself * v.y;
    } else {
        acc[0] = wself * ld1(d);
    }

    int j = row_ptr[d];
    const int hi = row_ptr[d + 1];
    for (; j + 3 < hi; j += 4) {
        int2 e0 = csr[j + 0];
        int2 e1 = csr[j + 1];
        int2 e2 = csr[j + 2];
        int2 e3 = csr[j + 3];
        float w0 = __int_as_float(e0.y), w1 = __int_as_float(e1.y);
        float w2 = __int_as_float(e2.y), w3 = __int_as_float(e3.y);
        if (VL == 2) {
            float2 v0 = ld2(e0.x);
            float2 v1 = ld2(e1.x);
            float2 v2 = ld2(e2.x);
            float2 v3 = ld2(e3.x);
            acc[0] += w0 * v0.x + w1 * v1.x + w2 * v2.x + w3 * v3.x;
            acc[1] += w0 * v0.y + w1 * v1.y + w2 * v2.y + w3 * v3.y;
        } else {
            acc[0] += w0 * ld1(e0.x) + w1 * ld1(e1.x) + w2 * ld1(e2.x) + w3 * ld1(e3.x);
        }
    }
    for (; j < hi; ++j) {
        int2 a = csr[j];
        float wa = __int_as_float(a.y);
        if (VL == 2) {
            float2 va = ld2(a.x);
            acc[0] += wa * va.x;
            acc[1] += wa * va.y;
        } else {
            acc[0] += wa * ld1(a.x);
        }
    }

    if (BIAS) {
        if (VL == 2) {
            float2 b = *(const float2*)(bias + c);
            acc[0] += b.x;
            acc[1] += b.y;
        } else {
            acc[0] += bias[c];
        }
    }
    if (RELU) {
#pragma unroll
        for (int v = 0; v < VL; ++v) acc[v] = fmaxf(acc[v], 0.f);
    }
    if constexpr (HOUT) {
        if (VL == 2) {
            *(__half2*)((__half*)out_ + (size_t)d * outs + c) = __floats2half2_rn(acc[0], acc[1]);
        } else {
            ((__half*)out_)[(size_t)d * outs + c] = __float2half(acc[0]);
        }
    } else {
        if (VL == 2) {
            *(float2*)((float*)out_ + (size_t)d * outs + c) = make_float2(acc[0], acc[1]);
        } else {
            ((float*)out_)[(size_t)d * outs + c] = acc[0];
        }
    }
}

// ---------------- fp16 MFMA GEMM: C[M,CN] = A[M,K] @ W[K,CN] (+bias,+relu), fp16 out ----
template <int K, int CN, bool BIAS, bool RELU>
__global__ __launch_bounds__(256) void k_gemm_mfma(const _Float16* __restrict__ A,
                                                   const char* __restrict__ wt,
                                                   const float* __restrict__ bias,
                                                   _Float16* __restrict__ C, int M) {
    constexpr int T = K / 32;
    constexpr int NT = CN / 16;
    __shared__ __align__(16) char wlds[CN * K * 2];
    const int tid = threadIdx.x;
    for (int i = tid; i < CN * K / 8; i += 256)
        ((float4*)wlds)[i] = ((const float4*)wt)[i];
    __syncthreads();

    const int l = tid & 63;
    const int w = tid >> 6;
    const int r0 = blockIdx.x * 128 + w * 32;
    const int lm = l & 15;
    const int lg = l >> 4;
    const int sw = (l & 7) << 4;

    half8 af[2][T];
#pragma unroll
    for (int s = 0; s < 2; ++s) {
        int row = r0 + s * 16 + lm;
        row = row < M ? row : M - 1;
        const _Float16* ap = A + (size_t)row * K + lg * 8;
#pragma unroll
        for (int t = 0; t < T; ++t) af[s][t] = *(const half8*)(ap + t * 32);
    }

    f32x4 acc[2][NT] = {};
#pragma unroll
    for (int j = 0; j < NT; ++j) {
        const int n = j * 16 + lm;
        const char* bp = wlds + n * (2 * K);
        half8 bf[T];
#pragma unroll
        for (int t = 0; t < T; ++t)
            bf[t] = *(const half8*)(bp + ((t * 64 + lg * 16) ^ sw));
#pragma unroll
        for (int s = 0; s < 2; ++s)
#pragma unroll
            for (int t = 0; t < T; ++t)
                acc[s][j] = __builtin_amdgcn_mfma_f32_16x16x32_f16(bf[t], af[s][t], acc[s][j], 0, 0, 0);
    }

#pragma unroll
    for (int s = 0; s < 2; ++s) {
        const int m = r0 + s * 16 + lm;
        if (m >= M) continue;
#pragma unroll
        for (int j = 0; j < NT; ++j) {
            const int n0 = j * 16 + lg * 4;
            f32x4 v = acc[s][j];
            if (BIAS) {
                float4 b = *(const float4*)(bias + n0);
                v[0] += b.x; v[1] += b.y; v[2] += b.z; v[3] += b.w;
            }
            if (RELU) {
                v[0] = fmaxf(v[0], 0.f); v[1] = fmaxf(v[1], 0.f);
                v[2] = fmaxf(v[2], 0.f); v[3] = fmaxf(v[3], 0.f);
            }
            union { float2 f; __half2 h[2]; } u;
            u.h[0] = __floats2half2_rn(v[0], v[1]);
            u.h[1] = __floats2half2_rn(v[2], v[3]);
            *(float2*)(C + (size_t)m * CN + n0) = u.f;
        }
    }
}

extern "C" void kernel_launch(void* const* d_in, const int* in_sizes, int n_in,
                              void* d_out, int out_size, void* d_ws, size_t ws_size,
                              hipStream_t stream) {
    const float* x  = (const float*)d_in[0];
    const int* ei   = (const int*)d_in[1];   // int32 (JAX x64 disabled)
    const float* W1 = (const float*)d_in[2];
    const float* b1 = (const float*)d_in[3];
    const float* W2 = (const float*)d_in[4];
    const float* b2 = (const float*)d_in[5];
    const float* W3 = (const float*)d_in[6];
    const float* b3 = (const float*)d_in[7];
    float* out = (float*)d_out;

    const int N = in_sizes[0] / 128;  // 100000
    const int E = in_sizes[1] / 2;    // 1600000
    const int* dst = ei + E;
    const int NB = cdiv(N, 1 << NBSH);  // buckets

    // workspace layout builder; slot = ebuf (bucketed, E*8B) or cur (fallback, N*4B)
    char* base = (char*)d_ws;
    size_t off = 0;
    auto take = [&](size_t bytes) {
        char* r = base + off;
        off += (bytes + 255) & ~(size_t)255;
        return r;
    };
    float* dis; int* deg; int* tmp; int* bsum; int* row_ptr; int* bcur;
    int2* csr; char* slot; _Float16 *xh, *a1, *h1, *t2, *h2, *t3;
    char *wt1, *wt2, *wt3;
    bool BUCKET = true;
    for (int pass = 0; pass < 2; ++pass) {
        off = 0;
        dis     = (float*)take((size_t)N * 4);
        deg     = (int*)take((size_t)N * 4);
        tmp     = (int*)take((size_t)N * 4);
        bsum    = (int*)take((size_t)1024 * 4);
        row_ptr = (int*)take((size_t)(N + 1) * 4);
        bcur    = (int*)take((size_t)NB * BPAD * 4);
        csr     = (int2*)take((size_t)E * 8);
        slot    = take(BUCKET ? (size_t)E * 8 : (size_t)N * 4);
        xh      = (_Float16*)take((size_t)N * 128 * 2);
        a1      = (_Float16*)take((size_t)N * 128 * 2);
        h1      = (_Float16*)take((size_t)N * 256 * 2);
        t2      = (_Float16*)take((size_t)N * 128 * 2);
        h2      = (_Float16*)take((size_t)N * 128 * 2);
        t3      = (_Float16*)take((size_t)N * 64 * 2);
        wt1     = take(256 * 128 * 2);
        wt2     = take(128 * 256 * 2);
        wt3     = take(64 * 128 * 2);
        if (off <= ws_size) break;
        BUCKET = false;  // retry with small slot
    }
    int2* ebuf = (int2*)slot;
    int* cur   = (int*)slot;

    const int nb = cdiv(N, 1024);

    // ---- CSR build (reused by all 3 layers) ----
    k_zero_i<<<cdiv(N, 256), 256, 0, stream>>>(deg, N);
    k_count<<<cdiv(E, 256), 256, 0, stream>>>(dst, deg, E);
    k_scan1<<<nb, 1024, 0, stream>>>(deg, tmp, bsum, N);
    k_scan2<<<1, 1024, 0, stream>>>(bsum, nb);
    k_scan3<<<cdiv(N + 1, 1024), 1024, 0, stream>>>(deg, tmp, bsum, row_ptr, dis, bcur,
                                                    BUCKET ? nullptr : cur, N, nb);
    if (BUCKET) {
        k_passA<<<cdiv(E, 256), 256, 0, stream>>>(ei, bcur, ebuf, E);
        k_passB<<<NB, 256, 0, stream>>>(row_ptr, dis, ebuf, csr, N);
    } else {
        k_scatter<<<cdiv(E, 256), 256, 0, stream>>>(ei, dis, cur, csr, E);
    }

    // ---- prep: x -> fp16; weights -> swizzled fp16 W^T ----
    k_cvt_h<<<cdiv((long long)N * 32, 256), 256, 0, stream>>>(x, (__half*)xh, (long long)N * 32);
    k_prep_wt<128, 256><<<cdiv(256 * 16, 256), 256, 0, stream>>>(W1, wt1);
    k_prep_wt<256, 128><<<cdiv(128 * 32, 256), 256, 0, stream>>>(W2, wt2);
    k_prep_wt<128, 64><<<cdiv(64 * 16, 256), 256, 0, stream>>>(W3, wt3);

    const int gA = cdiv((long long)N * 64, 256);  // agg: 1 wave/row
    const int gG = cdiv(N, 128);                  // gemm: 128 rows/block

    // ---- layer 1: a1 = agg(xh); h1 = relu(a1@W1 + b1) ----
    k_agg_csr<128, false, false, true, true><<<gA, 256, 0, stream>>>(row_ptr, csr, dis, xh, 128, a1, 128, nullptr, N);
    k_gemm_mfma<128, 256, true, true><<<gG, 256, 0, stream>>>(a1, wt1, b1, h1, N);

    // ---- layer 2: t2 = h1@W2; h2 = relu(agg(t2) + b2) ----
    k_gemm_mfma<256, 128, false, false><<<gG, 256, 0, stream>>>(h1, wt2, nullptr, t2, N);
    k_agg_csr<128, true, true, true, true><<<gA, 256, 0, stream>>>(row_ptr, csr, dis, t2, 128, h2, 128, b2, N);

    // ---- layer 3: t3 = h2@W3; out = agg(t3) + b3 ----
    k_gemm_mfma<128, 64, false, false><<<gG, 256, 0, stream>>>(h2, wt3, nullptr, t3, N);
    k_agg_csr<64, true, false, true, false><<<gA, 256, 0, stream>>>(row_ptr, csr, dis, t3, 64, out, 64, b3, N);
}

// Round 9
// 383.641 us; speedup vs baseline: 1.3127x; 1.3127x over previous
//
#include <hip/hip_runtime.h>
#include <hip/hip_fp16.h>

static inline int cdiv(long long a, long long b) { return (int)((a + b - 1) / b); }

typedef _Float16 half8 __attribute__((ext_vector_type(8)));
typedef float f32x4 __attribute__((ext_vector_type(4)));

#define NBSH 8            // 256 dsts per bucket
#define BCAP 6144         // bucket capacity in ebuf (avg 4096 for this graph; +50%)
#define BCHUNK 8192       // edges per k_bin block

// ---------------- binned CSR build (no global per-dst atomics) ----------------
__global__ void k_zero_bin(int* bcnt, int* ovf_cnt, int nbk) {
    int t = blockIdx.x * blockDim.x + threadIdx.x;
    if (t < nbk) bcnt[t] = 0;
    if (t == 0) *ovf_cnt = 0;
}

// chunk-local histogram + bulk range reservation + scatter {src,dst} into bucket regions
__global__ __launch_bounds__(256) void k_bin(const int* __restrict__ ei, int E, int nbk,
                                             int* __restrict__ bcnt,
                                             int2* __restrict__ ebuf,
                                             int2* __restrict__ ovf, int* __restrict__ ovf_cnt) {
    __shared__ int hist[1024];
    __shared__ int base[1024];
    const int tid = threadIdx.x;
    const int e0 = blockIdx.x * BCHUNK;
    if (e0 >= E) return;
    const int n = min(BCHUNK, E - e0);
    const int* __restrict__ srcs = ei + e0;
    const int* __restrict__ dsts = ei + E + e0;

    for (int i = tid; i < nbk; i += 256) hist[i] = 0;
    __syncthreads();
    for (int i = tid; i < n; i += 256) atomicAdd(&hist[dsts[i] >> NBSH], 1);
    __syncthreads();
    for (int b = tid; b < nbk; b += 256) {
        int h = hist[b];
        base[b] = h ? atomicAdd(&bcnt[b], h) : 0;
        hist[b] = 0;  // reuse as local offset
    }
    __syncthreads();
    for (int i = tid; i < n; i += 256) {
        int d = dsts[i];
        int s = srcs[i];
        int b = d >> NBSH;
        int pos = base[b] + atomicAdd(&hist[b], 1);
        if (pos < BCAP) {
            ebuf[(size_t)b * BCAP + pos] = make_int2(s, d);
        } else {
            int op = atomicAdd(ovf_cnt, 1);
            ovf[op] = make_int2(s, d);
        }
    }
}

// exclusive scan of true bucket sizes -> bbase; row_ptr[N] = total
__global__ __launch_bounds__(1024) void k_bscan(const int* __restrict__ bcnt,
                                                int* __restrict__ bbase,
                                                int* __restrict__ row_ptr, int nbk, int N) {
    __shared__ int s[1024];
    const int t = threadIdx.x;
    int v = (t < nbk) ? bcnt[t] : 0;
    s[t] = v;
    __syncthreads();
    for (int off = 1; off < 1024; off <<= 1) {
        int u = (t >= off) ? s[t - off] : 0;
        __syncthreads();
        s[t] += u;
        __syncthreads();
    }
    if (t < nbk) bbase[t] = s[t] - v;
    if (t == nbk - 1) row_ptr[N] = s[t];
}

// per bucket: local degree count + scan -> row_ptr, dis
__global__ __launch_bounds__(256) void k_passB1(const int* __restrict__ bcnt,
                                                const int* __restrict__ bbase,
                                                const int2* __restrict__ ebuf,
                                                const int2* __restrict__ ovf,
                                                const int* __restrict__ ovf_cnt,
                                                int* __restrict__ row_ptr,
                                                float* __restrict__ dis, int N) {
    __shared__ int ldeg[256];
    __shared__ int sc[256];
    const int tid = threadIdx.x;
    const int b = blockIdx.x;
    const int d0 = b << NBSH;
    const int dn = min(1 << NBSH, N - d0);
    ldeg[tid] = 0;
    __syncthreads();
    const int sz = min(bcnt[b], BCAP);
    const int2* __restrict__ reg = ebuf + (size_t)b * BCAP;
    for (int i = tid; i < sz; i += 256) atomicAdd(&ldeg[reg[i].y - d0], 1);
    const int oc = *ovf_cnt;
    for (int i = tid; i < oc; i += 256) {
        int d = ovf[i].y;
        if ((d >> NBSH) == b) atomicAdd(&ldeg[d - d0], 1);
    }
    __syncthreads();
    sc[tid] = ldeg[tid];
    __syncthreads();
    for (int off = 1; off < 256; off <<= 1) {
        int u = (tid >= off) ? sc[tid - off] : 0;
        __syncthreads();
        sc[tid] += u;
        __syncthreads();
    }
    if (tid < dn) {
        row_ptr[d0 + tid] = bbase[b] + sc[tid] - ldeg[tid];
        dis[d0 + tid] = rsqrtf((float)(ldeg[tid] + 1));  // +1 self-loop
    }
}

// per bucket: scatter {src, w} into csr (cursors from row_ptr, in LDS)
__global__ __launch_bounds__(256) void k_passB2(const int* __restrict__ bcnt,
                                                const int2* __restrict__ ebuf,
                                                const int2* __restrict__ ovf,
                                                const int* __restrict__ ovf_cnt,
                                                const int* __restrict__ row_ptr,
                                                const float* __restrict__ dis,
                                                int2* __restrict__ csr, int N) {
    __shared__ int lcur[256];
    const int tid = threadIdx.x;
    const int b = blockIdx.x;
    const int d0 = b << NBSH;
    const int dn = min(1 << NBSH, N - d0);
    lcur[tid] = (tid < dn) ? row_ptr[d0 + tid] : 0;
    __syncthreads();
    const int sz = min(bcnt[b], BCAP);
    const int2* __restrict__ reg = ebuf + (size_t)b * BCAP;
    for (int i = tid; i < sz; i += 256) {
        int2 sd = reg[i];
        float w = dis[sd.x] * dis[sd.y];
        int pos = atomicAdd(&lcur[sd.y - d0], 1);
        csr[pos] = make_int2(sd.x, __float_as_int(w));
    }
    const int oc = *ovf_cnt;
    for (int i = tid; i < oc; i += 256) {
        int2 sd = ovf[i];
        if ((sd.y >> NBSH) != b) continue;
        float w = dis[sd.x] * dis[sd.y];
        int pos = atomicAdd(&lcur[sd.y - d0], 1);
        csr[pos] = make_int2(sd.x, __float_as_int(w));
    }
}

// ---------------- fallback CSR build (round-7 path, used only if ws too small) ----------------
__global__ void k_zero_i(int* p, int n) {
    int t = blockIdx.x * blockDim.x + threadIdx.x;
    if (t < n) p[t] = 0;
}

__global__ void k_count(const int* __restrict__ dst, int* __restrict__ deg, int E) {
    int t = blockIdx.x * blockDim.x + threadIdx.x;
    if (t < E) atomicAdd(&deg[dst[t]], 1);
}

__global__ __launch_bounds__(1024) void k_scan1(const int* __restrict__ deg,
                                                int* __restrict__ tmp,
                                                int* __restrict__ bsum, int n) {
    __shared__ int s[1024];
    const int t = threadIdx.x;
    const int i = blockIdx.x * 1024 + t;
    int v = (i < n) ? deg[i] : 0;
    s[t] = v;
    __syncthreads();
    for (int off = 1; off < 1024; off <<= 1) {
        int u = (t >= off) ? s[t - off] : 0;
        __syncthreads();
        s[t] += u;
        __syncthreads();
    }
    if (i < n) tmp[i] = s[t];
    if (t == 1023) bsum[blockIdx.x] = s[1023];
}

__global__ __launch_bounds__(1024) void k_scan2(int* __restrict__ bsum, int nb) {
    __shared__ int s[1024];
    const int t = threadIdx.x;
    s[t] = (t < nb) ? bsum[t] : 0;
    __syncthreads();
    for (int off = 1; off < 1024; off <<= 1) {
        int u = (t >= off) ? s[t - off] : 0;
        __syncthreads();
        s[t] += u;
        __syncthreads();
    }
    if (t < nb) bsum[t] = s[t];
}

__global__ __launch_bounds__(1024) void k_scan3(const int* __restrict__ deg,
                                                const int* __restrict__ tmp,
                                                const int* __restrict__ bsum,
                                                int* __restrict__ row_ptr,
                                                float* __restrict__ dis,
                                                int* __restrict__ cur, int n, int nb) {
    const int i = blockIdx.x * 1024 + threadIdx.x;
    if (i < n) {
        int off = (blockIdx.x == 0) ? 0 : bsum[blockIdx.x - 1];
        int dgi = deg[i];
        int r = tmp[i] - dgi + off;
        row_ptr[i] = r;
        dis[i] = rsqrtf((float)(dgi + 1));
        cur[i] = r;
    } else if (i == n) {
        row_ptr[n] = bsum[nb - 1];
    }
}

__global__ void k_scatter(const int* __restrict__ ei, const float* __restrict__ dis,
                          int* __restrict__ cur, int2* __restrict__ csr, int E) {
    int e = blockIdx.x * blockDim.x + threadIdx.x;
    if (e >= E) return;
    int s = ei[e];
    int d = ei[e + E];
    float w = dis[s] * dis[d];
    int pos = atomicAdd(&cur[d], 1);
    csr[pos] = make_int2(s, __float_as_int(w));
}

// ---------------- fp32 -> fp16 convert ----------------
__global__ __launch_bounds__(256) void k_cvt_h(const float* __restrict__ in,
                                               __half* __restrict__ out, long long n4) {
    long long t = (long long)blockIdx.x * blockDim.x + threadIdx.x;
    if (t >= n4) return;
    float4 v = *(const float4*)(in + t * 4);
    union { float2 f; __half2 h[2]; } u;
    u.h[0] = __floats2half2_rn(v.x, v.y);
    u.h[1] = __floats2half2_rn(v.z, v.w);
    *(float2*)(out + t * 4) = u.f;
}

// ---------------- weight prep: W fp32 [K][CN] -> swizzled fp16 W^T [CN][K] ----------------
template <int K, int CN>
__global__ void k_prep_wt(const float* __restrict__ W, char* __restrict__ wt) {
    constexpr int CH = K / 8;
    int id = blockIdx.x * blockDim.x + threadIdx.x;
    if (id >= CN * CH) return;
    int n = id / CH, c = id % CH;
    half8 h;
#pragma unroll
    for (int j = 0; j < 8; ++j) h[j] = (_Float16)W[(size_t)(c * 8 + j) * CN + n];
    *(half8*)(wt + (size_t)n * (2 * K) + ((c * 16) ^ ((n & 7) << 4))) = h;
}

// ---------------- fused aggregation: one wave per output row ----------------
template <int C, bool BIAS, bool RELU, bool HIN, bool HOUT>
__global__ __launch_bounds__(256) void k_agg_csr(const int* __restrict__ row_ptr,
                                                 const int2* __restrict__ csr,
                                                 const float* __restrict__ dis,
                                                 const void* __restrict__ in_, int ins,
                                                 void* __restrict__ out_, int outs,
                                                 const float* __restrict__ bias, int N) {
    constexpr int VL = C / 64;
    const int wave = (int)(((long long)blockIdx.x * blockDim.x + threadIdx.x) >> 6);
    const int lane = threadIdx.x & 63;
    if (wave >= N) return;
    const int d = wave;
    const int c = lane * VL;
    const float dd = dis[d];
    const float wself = dd * dd;

    auto ld2 = [&](int row) -> float2 {
        if constexpr (HIN) {
            __half2 h = *(const __half2*)((const __half*)in_ + (size_t)row * ins + c);
            return __half22float2(h);
        } else {
            return *(const float2*)((const float*)in_ + (size_t)row * ins + c);
        }
    };
    auto ld1 = [&](int row) -> float {
        if constexpr (HIN) {
            return __half2float(((const __half*)in_)[(size_t)row * ins + c]);
        } else {
            return ((const float*)in_)[(size_t)row * ins + c];
        }
    };

    float acc[VL];
    if (VL == 2) {
        float2 v = ld2(d);
        acc[0] = wself * v.x;
        acc[1] = wself * v.y;
    } else {
        acc[0] = wself * ld1(d);
    }

    int j = row_ptr[d];
    const int hi = row_ptr[d + 1];
    for (; j + 3 < hi; j += 4) {
        int2 e0 = csr[j + 0];
        int2 e1 = csr[j + 1];
        int2 e2 = csr[j + 2];
        int2 e3 = csr[j + 3];
        float w0 = __int_as_float(e0.y), w1 = __int_as_float(e1.y);
        float w2 = __int_as_float(e2.y), w3 = __int_as_float(e3.y);
        if (VL == 2) {
            float2 v0 = ld2(e0.x);
            float2 v1 = ld2(e1.x);
            float2 v2 = ld2(e2.x);
            float2 v3 = ld2(e3.x);
            acc[0] += w0 * v0.x + w1 * v1.x + w2 * v2.x + w3 * v3.x;
            acc[1] += w0 * v0.y + w1 * v1.y + w2 * v2.y + w3 * v3.y;
        } else {
            acc[0] += w0 * ld1(e0.x) + w1 * ld1(e1.x) + w2 * ld1(e2.x) + w3 * ld1(e3.x);
        }
    }
    for (; j < hi; ++j) {
        int2 a = csr[j];
        float wa = __int_as_float(a.y);
        if (VL == 2) {
            float2 va = ld2(a.x);
            acc[0] += wa * va.x;
            acc[1] += wa * va.y;
        } else {
            acc[0] += wa * ld1(a.x);
        }
    }

    if (BIAS) {
        if (VL == 2) {
            float2 b = *(const float2*)(bias + c);
            acc[0] += b.x;
            acc[1] += b.y;
        } else {
            acc[0] += bias[c];
        }
    }
    if (RELU) {
#pragma unroll
        for (int v = 0; v < VL; ++v) acc[v] = fmaxf(acc[v], 0.f);
    }
    if constexpr (HOUT) {
        if (VL == 2) {
            *(__half2*)((__half*)out_ + (size_t)d * outs + c) = __floats2half2_rn(acc[0], acc[1]);
        } else {
            ((__half*)out_)[(size_t)d * outs + c] = __float2half(acc[0]);
        }
    } else {
        if (VL == 2) {
            *(float2*)((float*)out_ + (size_t)d * outs + c) = make_float2(acc[0], acc[1]);
        } else {
            ((float*)out_)[(size_t)d * outs + c] = acc[0];
        }
    }
}

// ---------------- fp16 MFMA GEMM: C[M,CN] = A[M,K] @ W[K,CN] (+bias,+relu), fp16 out ----
template <int K, int CN, bool BIAS, bool RELU>
__global__ __launch_bounds__(256) void k_gemm_mfma(const _Float16* __restrict__ A,
                                                   const char* __restrict__ wt,
                                                   const float* __restrict__ bias,
                                                   _Float16* __restrict__ C, int M) {
    constexpr int T = K / 32;
    constexpr int NT = CN / 16;
    __shared__ __align__(16) char wlds[CN * K * 2];
    const int tid = threadIdx.x;
    for (int i = tid; i < CN * K / 8; i += 256)
        ((float4*)wlds)[i] = ((const float4*)wt)[i];
    __syncthreads();

    const int l = tid & 63;
    const int w = tid >> 6;
    const int r0 = blockIdx.x * 128 + w * 32;
    const int lm = l & 15;
    const int lg = l >> 4;
    const int sw = (l & 7) << 4;

    half8 af[2][T];
#pragma unroll
    for (int s = 0; s < 2; ++s) {
        int row = r0 + s * 16 + lm;
        row = row < M ? row : M - 1;
        const _Float16* ap = A + (size_t)row * K + lg * 8;
#pragma unroll
        for (int t = 0; t < T; ++t) af[s][t] = *(const half8*)(ap + t * 32);
    }

    f32x4 acc[2][NT] = {};
#pragma unroll
    for (int j = 0; j < NT; ++j) {
        const int n = j * 16 + lm;
        const char* bp = wlds + n * (2 * K);
        half8 bf[T];
#pragma unroll
        for (int t = 0; t < T; ++t)
            bf[t] = *(const half8*)(bp + ((t * 64 + lg * 16) ^ sw));
#pragma unroll
        for (int s = 0; s < 2; ++s)
#pragma unroll
            for (int t = 0; t < T; ++t)
                acc[s][j] = __builtin_amdgcn_mfma_f32_16x16x32_f16(bf[t], af[s][t], acc[s][j], 0, 0, 0);
    }

#pragma unroll
    for (int s = 0; s < 2; ++s) {
        const int m = r0 + s * 16 + lm;
        if (m >= M) continue;
#pragma unroll
        for (int j = 0; j < NT; ++j) {
            const int n0 = j * 16 + lg * 4;
            f32x4 v = acc[s][j];
            if (BIAS) {
                float4 b = *(const float4*)(bias + n0);
                v[0] += b.x; v[1] += b.y; v[2] += b.z; v[3] += b.w;
            }
            if (RELU) {
                v[0] = fmaxf(v[0], 0.f); v[1] = fmaxf(v[1], 0.f);
                v[2] = fmaxf(v[2], 0.f); v[3] = fmaxf(v[3], 0.f);
            }
            union { float2 f; __half2 h[2]; } u;
            u.h[0] = __floats2half2_rn(v[0], v[1]);
            u.h[1] = __floats2half2_rn(v[2], v[3]);
            *(float2*)(C + (size_t)m * CN + n0) = u.f;
        }
    }
}

extern "C" void kernel_launch(void* const* d_in, const int* in_sizes, int n_in,
                              void* d_out, int out_size, void* d_ws, size_t ws_size,
                              hipStream_t stream) {
    const float* x  = (const float*)d_in[0];
    const int* ei   = (const int*)d_in[1];   // int32 (JAX x64 disabled)
    const float* W1 = (const float*)d_in[2];
    const float* b1 = (const float*)d_in[3];
    const float* W2 = (const float*)d_in[4];
    const float* b2 = (const float*)d_in[5];
    const float* W3 = (const float*)d_in[6];
    const float* b3 = (const float*)d_in[7];
    float* out = (float*)d_out;

    const int N = in_sizes[0] / 128;  // 100000
    const int E = in_sizes[1] / 2;    // 1600000
    const int* dst = ei + E;
    const int nbk = cdiv(N, 1 << NBSH);  // 391 buckets

    // workspace layout (256B-aligned); aliased fp16 buffers:
    //   t2 := a1, h2 := h1, t3 := xh  (lifetimes verified disjoint)
    char* base = (char*)d_ws;
    size_t off = 0;
    auto take = [&](size_t bytes) {
        char* r = base + off;
        off += (bytes + 255) & ~(size_t)255;
        return r;
    };
    float* dis    = (float*)take((size_t)N * 4);
    int* row_ptr  = (int*)take((size_t)(N + 1) * 4);
    int* bcnt     = (int*)take((size_t)nbk * 4);
    int* bbase    = (int*)take((size_t)nbk * 4);
    int* ovf_cnt  = (int*)take(256);
    int2* csr     = (int2*)take((size_t)E * 8);
    char* binmem  = take((size_t)nbk * BCAP * 8);  // ebuf; fallback scratch aliases here
    int2* ovf     = (int2*)take((size_t)E * 8);
    _Float16* xh  = (_Float16*)take((size_t)N * 128 * 2);
    _Float16* a1  = (_Float16*)take((size_t)N * 128 * 2);
    _Float16* h1  = (_Float16*)take((size_t)N * 256 * 2);
    char* wt1     = take(256 * 128 * 2);
    char* wt2     = take(128 * 256 * 2);
    char* wt3     = take(64 * 128 * 2);
    _Float16* t2 = a1;   // a1 dead after gemm1
    _Float16* h2 = h1;   // h1 dead after gemm2
    _Float16* t3 = xh;   // xh dead after agg1

    const bool BUCKET = (off <= ws_size) && (nbk <= 1024);

    if (BUCKET) {
        int2* ebuf = (int2*)binmem;
        k_zero_bin<<<cdiv(nbk + 1, 256), 256, 0, stream>>>(bcnt, ovf_cnt, nbk);
        k_bin<<<cdiv(E, BCHUNK), 256, 0, stream>>>(ei, E, nbk, bcnt, ebuf, ovf, ovf_cnt);
        k_bscan<<<1, 1024, 0, stream>>>(bcnt, bbase, row_ptr, nbk, N);
        k_passB1<<<nbk, 256, 0, stream>>>(bcnt, bbase, ebuf, ovf, ovf_cnt, row_ptr, dis, N);
        k_passB2<<<nbk, 256, 0, stream>>>(bcnt, ebuf, ovf, ovf_cnt, row_ptr, dis, csr, N);
    } else {
        // fallback: round-7 exact CSR build in binmem scratch
        size_t o2 = 0;
        auto take2 = [&](size_t bytes) {
            char* r = binmem + o2;
            o2 += (bytes + 255) & ~(size_t)255;
            return r;
        };
        int* deg  = (int*)take2((size_t)N * 4);
        int* tmp  = (int*)take2((size_t)N * 4);
        int* bsum = (int*)take2((size_t)1024 * 4);
        int* cur  = (int*)take2((size_t)N * 4);
        const int nb = cdiv(N, 1024);
        k_zero_i<<<cdiv(N, 256), 256, 0, stream>>>(deg, N);
        k_count<<<cdiv(E, 256), 256, 0, stream>>>(dst, deg, E);
        k_scan1<<<nb, 1024, 0, stream>>>(deg, tmp, bsum, N);
        k_scan2<<<1, 1024, 0, stream>>>(bsum, nb);
        k_scan3<<<cdiv(N + 1, 1024), 1024, 0, stream>>>(deg, tmp, bsum, row_ptr, dis, cur, N, nb);
        k_scatter<<<cdiv(E, 256), 256, 0, stream>>>(ei, dis, cur, csr, E);
    }

    // ---- prep: x -> fp16; weights -> swizzled fp16 W^T ----
    k_cvt_h<<<cdiv((long long)N * 32, 256), 256, 0, stream>>>(x, (__half*)xh, (long long)N * 32);
    k_prep_wt<128, 256><<<cdiv(256 * 16, 256), 256, 0, stream>>>(W1, wt1);
    k_prep_wt<256, 128><<<cdiv(128 * 32, 256), 256, 0, stream>>>(W2, wt2);
    k_prep_wt<128, 64><<<cdiv(64 * 16, 256), 256, 0, stream>>>(W3, wt3);

    const int gA = cdiv((long long)N * 64, 256);  // agg: 1 wave/row
    const int gG = cdiv(N, 128);                  // gemm: 128 rows/block

    // ---- layer 1: a1 = agg(xh); h1 = relu(a1@W1 + b1) ----
    k_agg_csr<128, false, false, true, true><<<gA, 256, 0, stream>>>(row_ptr, csr, dis, xh, 128, a1, 128, nullptr, N);
    k_gemm_mfma<128, 256, true, true><<<gG, 256, 0, stream>>>(a1, wt1, b1, h1, N);

    // ---- layer 2: t2 = h1@W2; h2 = relu(agg(t2) + b2) ----
    k_gemm_mfma<256, 128, false, false><<<gG, 256, 0, stream>>>(h1, wt2, nullptr, t2, N);
    k_agg_csr<128, true, true, true, true><<<gA, 256, 0, stream>>>(row_ptr, csr, dis, t2, 128, h2, 128, b2, N);

    // ---- layer 3: t3 = h2@W3; out = agg(t3) + b3 ----
    k_gemm_mfma<128, 64, false, false><<<gG, 256, 0, stream>>>(h2, wt3, nullptr, t3, N);
    k_agg_csr<64, true, false, true, false><<<gA, 256, 0, stream>>>(row_ptr, csr, dis, t3, 64, out, 64, b3, N);
}

// Round 10
// 318.364 us; speedup vs baseline: 1.5818x; 1.2050x over previous
//
#include <hip/hip_runtime.h>
#include <hip/hip_fp16.h>

static inline int cdiv(long long a, long long b) { return (int)((a + b - 1) / b); }

typedef _Float16 half8 __attribute__((ext_vector_type(8)));
typedef float f32x4 __attribute__((ext_vector_type(4)));

#define NBSH 8            // 256 dsts per bucket
#define BCAP 6144         // bucket capacity in ebuf (avg 4096 for this graph; +50%)
#define BCHUNK 8192       // edges per k_bin block

// ---------------- binned CSR build (no global per-dst atomics) ----------------
__global__ void k_zero_bin(int* bcnt, int* ovf_cnt, int nbk) {
    int t = blockIdx.x * blockDim.x + threadIdx.x;
    if (t < nbk) bcnt[t] = 0;
    if (t == 0) *ovf_cnt = 0;
}

__global__ __launch_bounds__(256) void k_bin(const int* __restrict__ ei, int E, int nbk,
                                             int* __restrict__ bcnt,
                                             int2* __restrict__ ebuf,
                                             int2* __restrict__ ovf, int* __restrict__ ovf_cnt) {
    __shared__ int hist[1024];
    __shared__ int base[1024];
    const int tid = threadIdx.x;
    const int e0 = blockIdx.x * BCHUNK;
    if (e0 >= E) return;
    const int n = min(BCHUNK, E - e0);
    const int* __restrict__ srcs = ei + e0;
    const int* __restrict__ dsts = ei + E + e0;

    for (int i = tid; i < nbk; i += 256) hist[i] = 0;
    __syncthreads();
    for (int i = tid; i < n; i += 256) atomicAdd(&hist[dsts[i] >> NBSH], 1);
    __syncthreads();
    for (int b = tid; b < nbk; b += 256) {
        int h = hist[b];
        base[b] = h ? atomicAdd(&bcnt[b], h) : 0;
        hist[b] = 0;  // reuse as local offset
    }
    __syncthreads();
    for (int i = tid; i < n; i += 256) {
        int d = dsts[i];
        int s = srcs[i];
        int b = d >> NBSH;
        int pos = base[b] + atomicAdd(&hist[b], 1);
        if (pos < BCAP) {
            ebuf[(size_t)b * BCAP + pos] = make_int2(s, d);
        } else {
            int op = atomicAdd(ovf_cnt, 1);
            ovf[op] = make_int2(s, d);
        }
    }
}

__global__ __launch_bounds__(1024) void k_bscan(const int* __restrict__ bcnt,
                                                int* __restrict__ bbase,
                                                int* __restrict__ row_ptr, int nbk, int N) {
    __shared__ int s[1024];
    const int t = threadIdx.x;
    int v = (t < nbk) ? bcnt[t] : 0;
    s[t] = v;
    __syncthreads();
    for (int off = 1; off < 1024; off <<= 1) {
        int u = (t >= off) ? s[t - off] : 0;
        __syncthreads();
        s[t] += u;
        __syncthreads();
    }
    if (t < nbk) bbase[t] = s[t] - v;
    if (t == nbk - 1) row_ptr[N] = s[t];
}

__global__ __launch_bounds__(256) void k_passB1(const int* __restrict__ bcnt,
                                                const int* __restrict__ bbase,
                                                const int2* __restrict__ ebuf,
                                                const int2* __restrict__ ovf,
                                                const int* __restrict__ ovf_cnt,
                                                int* __restrict__ row_ptr,
                                                float* __restrict__ dis, int N) {
    __shared__ int ldeg[256];
    __shared__ int sc[256];
    const int tid = threadIdx.x;
    const int b = blockIdx.x;
    const int d0 = b << NBSH;
    const int dn = min(1 << NBSH, N - d0);
    ldeg[tid] = 0;
    __syncthreads();
    const int sz = min(bcnt[b], BCAP);
    const int2* __restrict__ reg = ebuf + (size_t)b * BCAP;
    for (int i = tid; i < sz; i += 256) atomicAdd(&ldeg[reg[i].y - d0], 1);
    const int oc = *ovf_cnt;
    for (int i = tid; i < oc; i += 256) {
        int d = ovf[i].y;
        if ((d >> NBSH) == b) atomicAdd(&ldeg[d - d0], 1);
    }
    __syncthreads();
    sc[tid] = ldeg[tid];
    __syncthreads();
    for (int off = 1; off < 256; off <<= 1) {
        int u = (tid >= off) ? sc[tid - off] : 0;
        __syncthreads();
        sc[tid] += u;
        __syncthreads();
    }
    if (tid < dn) {
        row_ptr[d0 + tid] = bbase[b] + sc[tid] - ldeg[tid];
        dis[d0 + tid] = rsqrtf((float)(ldeg[tid] + 1));  // +1 self-loop
    }
}

__global__ __launch_bounds__(256) void k_passB2(const int* __restrict__ bcnt,
                                                const int2* __restrict__ ebuf,
                                                const int2* __restrict__ ovf,
                                                const int* __restrict__ ovf_cnt,
                                                const int* __restrict__ row_ptr,
                                                const float* __restrict__ dis,
                                                int2* __restrict__ csr, int N) {
    __shared__ int lcur[256];
    const int tid = threadIdx.x;
    const int b = blockIdx.x;
    const int d0 = b << NBSH;
    const int dn = min(1 << NBSH, N - d0);
    lcur[tid] = (tid < dn) ? row_ptr[d0 + tid] : 0;
    __syncthreads();
    const int sz = min(bcnt[b], BCAP);
    const int2* __restrict__ reg = ebuf + (size_t)b * BCAP;
    for (int i = tid; i < sz; i += 256) {
        int2 sd = reg[i];
        float w = dis[sd.x] * dis[sd.y];
        int pos = atomicAdd(&lcur[sd.y - d0], 1);
        csr[pos] = make_int2(sd.x, __float_as_int(w));
    }
    const int oc = *ovf_cnt;
    for (int i = tid; i < oc; i += 256) {
        int2 sd = ovf[i];
        if ((sd.y >> NBSH) != b) continue;
        float w = dis[sd.x] * dis[sd.y];
        int pos = atomicAdd(&lcur[sd.y - d0], 1);
        csr[pos] = make_int2(sd.x, __float_as_int(w));
    }
}

// ---------------- fallback CSR build (round-7 path, used only if ws too small) ----------------
__global__ void k_zero_i(int* p, int n) {
    int t = blockIdx.x * blockDim.x + threadIdx.x;
    if (t < n) p[t] = 0;
}

__global__ void k_count(const int* __restrict__ dst, int* __restrict__ deg, int E) {
    int t = blockIdx.x * blockDim.x + threadIdx.x;
    if (t < E) atomicAdd(&deg[dst[t]], 1);
}

__global__ __launch_bounds__(1024) void k_scan1(const int* __restrict__ deg,
                                                int* __restrict__ tmp,
                                                int* __restrict__ bsum, int n) {
    __shared__ int s[1024];
    const int t = threadIdx.x;
    const int i = blockIdx.x * 1024 + t;
    int v = (i < n) ? deg[i] : 0;
    s[t] = v;
    __syncthreads();
    for (int off = 1; off < 1024; off <<= 1) {
        int u = (t >= off) ? s[t - off] : 0;
        __syncthreads();
        s[t] += u;
        __syncthreads();
    }
    if (i < n) tmp[i] = s[t];
    if (t == 1023) bsum[blockIdx.x] = s[1023];
}

__global__ __launch_bounds__(1024) void k_scan2(int* __restrict__ bsum, int nb) {
    __shared__ int s[1024];
    const int t = threadIdx.x;
    s[t] = (t < nb) ? bsum[t] : 0;
    __syncthreads();
    for (int off = 1; off < 1024; off <<= 1) {
        int u = (t >= off) ? s[t - off] : 0;
        __syncthreads();
        s[t] += u;
        __syncthreads();
    }
    if (t < nb) bsum[t] = s[t];
}

__global__ __launch_bounds__(1024) void k_scan3(const int* __restrict__ deg,
                                                const int* __restrict__ tmp,
                                                const int* __restrict__ bsum,
                                                int* __restrict__ row_ptr,
                                                float* __restrict__ dis,
                                                int* __restrict__ cur, int n, int nb) {
    const int i = blockIdx.x * 1024 + threadIdx.x;
    if (i < n) {
        int off = (blockIdx.x == 0) ? 0 : bsum[blockIdx.x - 1];
        int dgi = deg[i];
        int r = tmp[i] - dgi + off;
        row_ptr[i] = r;
        dis[i] = rsqrtf((float)(dgi + 1));
        cur[i] = r;
    } else if (i == n) {
        row_ptr[n] = bsum[nb - 1];
    }
}

__global__ void k_scatter(const int* __restrict__ ei, const float* __restrict__ dis,
                          int* __restrict__ cur, int2* __restrict__ csr, int E) {
    int e = blockIdx.x * blockDim.x + threadIdx.x;
    if (e >= E) return;
    int s = ei[e];
    int d = ei[e + E];
    float w = dis[s] * dis[d];
    int pos = atomicAdd(&cur[d], 1);
    csr[pos] = make_int2(s, __float_as_int(w));
}

// ---------------- fp32 -> fp16 convert ----------------
__global__ __launch_bounds__(256) void k_cvt_h(const float* __restrict__ in,
                                               __half* __restrict__ out, long long n4) {
    long long t = (long long)blockIdx.x * blockDim.x + threadIdx.x;
    if (t >= n4) return;
    float4 v = *(const float4*)(in + t * 4);
    union { float2 f; __half2 h[2]; } u;
    u.h[0] = __floats2half2_rn(v.x, v.y);
    u.h[1] = __floats2half2_rn(v.z, v.w);
    *(float2*)(out + t * 4) = u.f;
}

// ---------------- weight prep: W fp32 [K][CN] -> swizzled fp16 W^T [CN][K] ----------------
template <int K, int CN>
__global__ void k_prep_wt(const float* __restrict__ W, char* __restrict__ wt) {
    constexpr int CH = K / 8;
    int id = blockIdx.x * blockDim.x + threadIdx.x;
    if (id >= CN * CH) return;
    int n = id / CH, c = id % CH;
    half8 h;
#pragma unroll
    for (int j = 0; j < 8; ++j) h[j] = (_Float16)W[(size_t)(c * 8 + j) * CN + n];
    *(half8*)(wt + (size_t)n * (2 * K) + ((c * 16) ^ ((n & 7) << 4))) = h;
}

// ---------------- vectorized fused aggregation ----------------
// out[d][:] = (BIAS? b:0) + dis[d]^2*in[d][:] + sum_e w_e*in[src_e][:]; optional ReLU.
// C/8 lanes per row (16B half8 loads), 64/(C/8) rows per wave. fp16 in; fp16/fp32 out.
template <int C, bool BIAS, bool RELU, bool HOUT>
__global__ __launch_bounds__(256) void k_agg_v(const int* __restrict__ row_ptr,
                                               const int2* __restrict__ csr,
                                               const float* __restrict__ dis,
                                               const _Float16* __restrict__ in,
                                               void* __restrict__ out_,
                                               const float* __restrict__ bias, int N) {
    constexpr int LPR = C / 8;   // lanes per row
    constexpr int RPW = 64 / LPR;  // rows per wave
    const int wave = (int)(((long long)blockIdx.x * blockDim.x + threadIdx.x) >> 6);
    const int lane = threadIdx.x & 63;
    const int d = wave * RPW + lane / LPR;
    if (d >= N) return;
    const int c = (lane % LPR) * 8;
    const _Float16* __restrict__ inc = in + c;

    float acc[8];
    {
        half8 v = *(const half8*)(inc + (size_t)d * C);
        float dd = dis[d], ws = dd * dd;
#pragma unroll
        for (int k = 0; k < 8; ++k) acc[k] = ws * (float)v[k];
    }

    int j = row_ptr[d];
    const int hi = row_ptr[d + 1];
    for (; j + 3 < hi; j += 4) {  // 4 x 16B gathers in flight per lane
        int2 e0 = csr[j + 0];
        int2 e1 = csr[j + 1];
        int2 e2 = csr[j + 2];
        int2 e3 = csr[j + 3];
        half8 v0 = *(const half8*)(inc + (size_t)e0.x * C);
        half8 v1 = *(const half8*)(inc + (size_t)e1.x * C);
        half8 v2 = *(const half8*)(inc + (size_t)e2.x * C);
        half8 v3 = *(const half8*)(inc + (size_t)e3.x * C);
        float w0 = __int_as_float(e0.y), w1 = __int_as_float(e1.y);
        float w2 = __int_as_float(e2.y), w3 = __int_as_float(e3.y);
#pragma unroll
        for (int k = 0; k < 8; ++k)
            acc[k] += w0 * (float)v0[k] + w1 * (float)v1[k] + w2 * (float)v2[k] + w3 * (float)v3[k];
    }
    for (; j < hi; ++j) {
        int2 e0 = csr[j];
        half8 v0 = *(const half8*)(inc + (size_t)e0.x * C);
        float w0 = __int_as_float(e0.y);
#pragma unroll
        for (int k = 0; k < 8; ++k) acc[k] += w0 * (float)v0[k];
    }

    if (BIAS) {
        float4 b0 = *(const float4*)(bias + c);
        float4 b1 = *(const float4*)(bias + c + 4);
        acc[0] += b0.x; acc[1] += b0.y; acc[2] += b0.z; acc[3] += b0.w;
        acc[4] += b1.x; acc[5] += b1.y; acc[6] += b1.z; acc[7] += b1.w;
    }
    if (RELU) {
#pragma unroll
        for (int k = 0; k < 8; ++k) acc[k] = fmaxf(acc[k], 0.f);
    }
    if constexpr (HOUT) {
        half8 h;
#pragma unroll
        for (int k = 0; k < 8; ++k) h[k] = (_Float16)acc[k];
        *(half8*)((_Float16*)out_ + (size_t)d * C + c) = h;
    } else {
        float* o = (float*)out_ + (size_t)d * C + c;
        *(float4*)o = make_float4(acc[0], acc[1], acc[2], acc[3]);
        *(float4*)(o + 4) = make_float4(acc[4], acc[5], acc[6], acc[7]);
    }
}

// ---------------- fp16 MFMA GEMM: C[M,CN] = A[M,K] @ W[K,CN] (+bias,+relu), fp16 out ----
template <int K, int CN, bool BIAS, bool RELU>
__global__ __launch_bounds__(256) void k_gemm_mfma(const _Float16* __restrict__ A,
                                                   const char* __restrict__ wt,
                                                   const float* __restrict__ bias,
                                                   _Float16* __restrict__ C, int M) {
    constexpr int T = K / 32;
    constexpr int NT = CN / 16;
    __shared__ __align__(16) char wlds[CN * K * 2];
    const int tid = threadIdx.x;
    for (int i = tid; i < CN * K / 8; i += 256)
        ((float4*)wlds)[i] = ((const float4*)wt)[i];
    __syncthreads();

    const int l = tid & 63;
    const int w = tid >> 6;
    const int r0 = blockIdx.x * 128 + w * 32;
    const int lm = l & 15;
    const int lg = l >> 4;
    const int sw = (l & 7) << 4;

    half8 af[2][T];
#pragma unroll
    for (int s = 0; s < 2; ++s) {
        int row = r0 + s * 16 + lm;
        row = row < M ? row : M - 1;
        const _Float16* ap = A + (size_t)row * K + lg * 8;
#pragma unroll
        for (int t = 0; t < T; ++t) af[s][t] = *(const half8*)(ap + t * 32);
    }

    f32x4 acc[2][NT] = {};
#pragma unroll
    for (int j = 0; j < NT; ++j) {
        const int n = j * 16 + lm;
        const char* bp = wlds + n * (2 * K);
        half8 bf[T];
#pragma unroll
        for (int t = 0; t < T; ++t)
            bf[t] = *(const half8*)(bp + ((t * 64 + lg * 16) ^ sw));
#pragma unroll
        for (int s = 0; s < 2; ++s)
#pragma unroll
            for (int t = 0; t < T; ++t)
                acc[s][j] = __builtin_amdgcn_mfma_f32_16x16x32_f16(bf[t], af[s][t], acc[s][j], 0, 0, 0);
    }

#pragma unroll
    for (int s = 0; s < 2; ++s) {
        const int m = r0 + s * 16 + lm;
        if (m >= M) continue;
#pragma unroll
        for (int j = 0; j < NT; ++j) {
            const int n0 = j * 16 + lg * 4;
            f32x4 v = acc[s][j];
            if (BIAS) {
                float4 b = *(const float4*)(bias + n0);
                v[0] += b.x; v[1] += b.y; v[2] += b.z; v[3] += b.w;
            }
            if (RELU) {
                v[0] = fmaxf(v[0], 0.f); v[1] = fmaxf(v[1], 0.f);
                v[2] = fmaxf(v[2], 0.f); v[3] = fmaxf(v[3], 0.f);
            }
            union { float2 f; __half2 h[2]; } u;
            u.h[0] = __floats2half2_rn(v[0], v[1]);
            u.h[1] = __floats2half2_rn(v[2], v[3]);
            *(float2*)(C + (size_t)m * CN + n0) = u.f;
        }
    }
}

extern "C" void kernel_launch(void* const* d_in, const int* in_sizes, int n_in,
                              void* d_out, int out_size, void* d_ws, size_t ws_size,
                              hipStream_t stream) {
    const float* x  = (const float*)d_in[0];
    const int* ei   = (const int*)d_in[1];   // int32 (JAX x64 disabled)
    const float* W1 = (const float*)d_in[2];
    const float* b1 = (const float*)d_in[3];
    const float* W2 = (const float*)d_in[4];
    const float* b2 = (const float*)d_in[5];
    const float* W3 = (const float*)d_in[6];
    const float* b3 = (const float*)d_in[7];
    float* out = (float*)d_out;

    const int N = in_sizes[0] / 128;  // 100000
    const int E = in_sizes[1] / 2;    // 1600000
    const int* dst = ei + E;
    const int nbk = cdiv(N, 1 << NBSH);  // 391 buckets

    // workspace layout (256B-aligned); aliased fp16 buffers:
    //   t2 := a1, h2 := h1, t3 := xh  (lifetimes disjoint)
    char* base = (char*)d_ws;
    size_t off = 0;
    auto take = [&](size_t bytes) {
        char* r = base + off;
        off += (bytes + 255) & ~(size_t)255;
        return r;
    };
    float* dis    = (float*)take((size_t)N * 4);
    int* row_ptr  = (int*)take((size_t)(N + 1) * 4);
    int* bcnt     = (int*)take((size_t)nbk * 4);
    int* bbase    = (int*)take((size_t)nbk * 4);
    int* ovf_cnt  = (int*)take(256);
    int2* csr     = (int2*)take((size_t)E * 8);
    char* binmem  = take((size_t)nbk * BCAP * 8);  // ebuf; fallback scratch aliases here
    int2* ovf     = (int2*)take((size_t)E * 8);
    _Float16* xh  = (_Float16*)take((size_t)N * 128 * 2);
    _Float16* a1  = (_Float16*)take((size_t)N * 128 * 2);
    _Float16* h1  = (_Float16*)take((size_t)N * 256 * 2);
    char* wt1     = take(256 * 128 * 2);
    char* wt2     = take(128 * 256 * 2);
    char* wt3     = take(64 * 128 * 2);
    _Float16* t2 = a1;   // a1 dead after gemm1
    _Float16* h2 = h1;   // h1 dead after gemm2
    _Float16* t3 = xh;   // xh dead after agg1

    const bool BUCKET = (off <= ws_size) && (nbk <= 1024);

    if (BUCKET) {
        int2* ebuf = (int2*)binmem;
        k_zero_bin<<<cdiv(nbk + 1, 256), 256, 0, stream>>>(bcnt, ovf_cnt, nbk);
        k_bin<<<cdiv(E, BCHUNK), 256, 0, stream>>>(ei, E, nbk, bcnt, ebuf, ovf, ovf_cnt);
        k_bscan<<<1, 1024, 0, stream>>>(bcnt, bbase, row_ptr, nbk, N);
        k_passB1<<<nbk, 256, 0, stream>>>(bcnt, bbase, ebuf, ovf, ovf_cnt, row_ptr, dis, N);
        k_passB2<<<nbk, 256, 0, stream>>>(bcnt, ebuf, ovf, ovf_cnt, row_ptr, dis, csr, N);
    } else {
        size_t o2 = 0;
        auto take2 = [&](size_t bytes) {
            char* r = binmem + o2;
            o2 += (bytes + 255) & ~(size_t)255;
            return r;
        };
        int* deg  = (int*)take2((size_t)N * 4);
        int* tmp  = (int*)take2((size_t)N * 4);
        int* bsum = (int*)take2((size_t)1024 * 4);
        int* cur  = (int*)take2((size_t)N * 4);
        const int nb = cdiv(N, 1024);
        k_zero_i<<<cdiv(N, 256), 256, 0, stream>>>(deg, N);
        k_count<<<cdiv(E, 256), 256, 0, stream>>>(dst, deg, E);
        k_scan1<<<nb, 1024, 0, stream>>>(deg, tmp, bsum, N);
        k_scan2<<<1, 1024, 0, stream>>>(bsum, nb);
        k_scan3<<<cdiv(N + 1, 1024), 1024, 0, stream>>>(deg, tmp, bsum, row_ptr, dis, cur, N, nb);
        k_scatter<<<cdiv(E, 256), 256, 0, stream>>>(ei, dis, cur, csr, E);
    }

    // ---- prep: x -> fp16; weights -> swizzled fp16 W^T ----
    k_cvt_h<<<cdiv((long long)N * 32, 256), 256, 0, stream>>>(x, (__half*)xh, (long long)N * 32);
    k_prep_wt<128, 256><<<cdiv(256 * 16, 256), 256, 0, stream>>>(W1, wt1);
    k_prep_wt<256, 128><<<cdiv(128 * 32, 256), 256, 0, stream>>>(W2, wt2);
    k_prep_wt<128, 64><<<cdiv(64 * 16, 256), 256, 0, stream>>>(W3, wt3);

    // agg grids: rows-per-wave depends on C
    const int gA128 = cdiv((long long)cdiv(N, 4) * 64, 256);  // C=128: 4 rows/wave
    const int gA64  = cdiv((long long)cdiv(N, 8) * 64, 256);  // C=64:  8 rows/wave
    const int gG = cdiv(N, 128);                              // gemm: 128 rows/block

    // ---- layer 1: a1 = agg(xh); h1 = relu(a1@W1 + b1) ----
    k_agg_v<128, false, false, true><<<gA128, 256, 0, stream>>>(row_ptr, csr, dis, xh, a1, nullptr, N);
    k_gemm_mfma<128, 256, true, true><<<gG, 256, 0, stream>>>(a1, wt1, b1, h1, N);

    // ---- layer 2: t2 = h1@W2; h2 = relu(agg(t2) + b2) ----
    k_gemm_mfma<256, 128, false, false><<<gG, 256, 0, stream>>>(h1, wt2, nullptr, t2, N);
    k_agg_v<128, true, true, true><<<gA128, 256, 0, stream>>>(row_ptr, csr, dis, t2, h2, b2, N);

    // ---- layer 3: t3 = h2@W3; out = agg(t3) + b3 ----
    k_gemm_mfma<128, 64, false, false><<<gG, 256, 0, stream>>>(h2, wt3, nullptr, t3, N);
    k_agg_v<64, true, false, false><<<gA64, 256, 0, stream>>>(row_ptr, csr, dis, t3, out, b3, N);
}